// Round 10
// baseline (191.285 us; speedup 1.0000x reference)
//
#include <hip/hip_runtime.h>
#include <math.h>

#define DEV __device__ __forceinline__

// ---- MFMA fragment types (gfx950 16x16x32 bf16) ----
using frag_ab = __attribute__((ext_vector_type(8))) short;  // 8 bf16 (4 VGPRs)
using frag_cd = __attribute__((ext_vector_type(4))) float;  // 4 fp32

static constexpr float SCALE_C = 0.04419417382415922f;  // 512^-0.5

// ---- bf16 helpers (RNE) ----
DEV unsigned short f2bf(float f) {
    unsigned u = __float_as_uint(f);
    unsigned r = (u + 0x7FFFu + ((u >> 16) & 1u)) >> 16;
    return (unsigned short)r;
}
DEV float bf2f(unsigned short h) { return __uint_as_float(((unsigned)h) << 16); }

DEV void unpack8(uint4 q, float f[8]) {
    f[0] = bf2f((unsigned short)(q.x & 0xFFFFu)); f[1] = bf2f((unsigned short)(q.x >> 16));
    f[2] = bf2f((unsigned short)(q.y & 0xFFFFu)); f[3] = bf2f((unsigned short)(q.y >> 16));
    f[4] = bf2f((unsigned short)(q.z & 0xFFFFu)); f[5] = bf2f((unsigned short)(q.z >> 16));
    f[6] = bf2f((unsigned short)(q.w & 0xFFFFu)); f[7] = bf2f((unsigned short)(q.w >> 16));
}
DEV uint4 pack8(const float f[8]) {
    uint4 q;
    q.x = (unsigned)f2bf(f[0]) | ((unsigned)f2bf(f[1]) << 16);
    q.y = (unsigned)f2bf(f[2]) | ((unsigned)f2bf(f[3]) << 16);
    q.z = (unsigned)f2bf(f[4]) | ((unsigned)f2bf(f[5]) << 16);
    q.w = (unsigned)f2bf(f[6]) | ((unsigned)f2bf(f[7]) << 16);
    return q;
}

// ---- order-preserving float<->u32 (monotone key) ----
DEV unsigned mono(float f) {
    unsigned u = __float_as_uint(f);
    return u ^ ((unsigned)((int)u >> 31) | 0x80000000u);
}
DEV float unmono(unsigned k) {
    unsigned u = (k & 0x80000000u) ? (k & 0x7FFFFFFFu) : ~k;
    return __uint_as_float(u);
}

// ---- async global->LDS 16B (direct-to-LDS DMA; dest = wave base + lane*16) ----
DEV void gload_lds16(const void* g, void* l) {
    __builtin_amdgcn_global_load_lds(
        (const __attribute__((address_space(1))) void*)g,
        (__attribute__((address_space(3))) void*)l, 16, 0, 0);
}

// ---- fused prep: z=0..4 LDS-tiled weight transposes ([K][512]f32 -> [512][K]bf16,
// wh/wt scaled by 0.5 for the rank-1 mean fold), z=5 feats conv ----
__global__ void k_prep(const float* __restrict__ feats, const float* __restrict__ fc1_w,
                       const float* __restrict__ wh_w, const float* __restrict__ wt_w,
                       const float* __restrict__ l1_w, const float* __restrict__ l2_w,
                       unsigned short* __restrict__ fb, unsigned short* __restrict__ wfc1T,
                       unsigned short* __restrict__ whT, unsigned short* __restrict__ wtT,
                       unsigned short* __restrict__ l1T, unsigned short* __restrict__ l2T) {
    const int z = blockIdx.z;
    const int tid = threadIdx.x;
    if (z == 5) {  // conv feats f32 -> bf16, grid-stride
        for (int i = (blockIdx.x * 256 + tid) * 4; i < 8192 * 384; i += 256 * 256 * 4) {
            float4 v = *(const float4*)(feats + i);
            ushort4 o;
            o.x = f2bf(v.x); o.y = f2bf(v.y); o.z = f2bf(v.z); o.w = f2bf(v.w);
            *(ushort4*)(fb + i) = o;
        }
        return;
    }
    const float* s = z == 0 ? fc1_w : z == 1 ? wh_w : z == 2 ? wt_w : z == 3 ? l1_w : l2_w;
    unsigned short* d = z == 0 ? wfc1T : z == 1 ? whT : z == 2 ? wtT : z == 3 ? l1T : l2T;
    const int K = z == 0 ? 384 : 512;
    const float scale = (z == 1 || z == 2) ? 0.5f : 1.0f;
    const int ntk = K >> 6;
    const int t = blockIdx.x;
    if (t >= ntk * 8) return;
    const int k0 = (t % ntk) * 64, n0 = (t / ntk) * 64;
    __shared__ short tile[64 * 68];  // [n][k], stride 68
    // phase 1: coalesced f32 read, transposed bf16 scatter into LDS
#pragma unroll
    for (int p = 0; p < 4; ++p) {
        int kk = p * 16 + (tid >> 4);
        int nn = (tid & 15) * 4;
        float4 v = *(const float4*)(s + (size_t)(k0 + kk) * 512 + n0 + nn);
        tile[(nn + 0) * 68 + kk] = (short)f2bf(v.x * scale);
        tile[(nn + 1) * 68 + kk] = (short)f2bf(v.y * scale);
        tile[(nn + 2) * 68 + kk] = (short)f2bf(v.z * scale);
        tile[(nn + 3) * 68 + kk] = (short)f2bf(v.w * scale);
    }
    __syncthreads();
    // phase 2: row reads from LDS, coalesced 16B global stores
#pragma unroll
    for (int p = 0; p < 2; ++p) {
        int rr = p * 32 + (tid >> 3);
        int cc = (tid & 7) * 8;
        const short* rp = &tile[rr * 68 + cc];
        uint2 a = *(const uint2*)(rp);
        uint2 b = *(const uint2*)(rp + 4);
        uint4 o = {a.x, a.y, b.x, b.y};
        *(uint4*)(d + (size_t)(n0 + rr) * K + k0 + cc) = o;
    }
}

// ---- rank-1 mean fold: cv = b + 0.5*colmean @ W (f32-exact) ----
__global__ __launch_bounds__(512) void k_rank1(
    const float* __restrict__ colsum, const float* __restrict__ wh_w,
    const float* __restrict__ wt_w, const float* __restrict__ wh_b,
    const float* __restrict__ wt_b, float* __restrict__ cvh, float* __restrict__ cvt) {
    const float* W = blockIdx.x ? wt_w : wh_w;
    const float* b = blockIdx.x ? wt_b : wh_b;
    float* cv = blockIdx.x ? cvt : cvh;
    const int n = threadIdx.x;
    float s = 0.f;
#pragma unroll 8
    for (int k = 0; k < 512; ++k) s += colsum[k] * W[k * 512 + n];
    cv[n] = b[n] + s * (0.5f / 8192.f);
}

// ---- staging: 128 rows x 64 bf16 (16KB), XOR-swizzled source, linear LDS dest ----
DEV void stage_async(const unsigned short* __restrict__ g, int ld, int k0, char* lds, int t) {
    const int sub = t >> 3;
    const int b = (t & 7) << 4;
    const int bs = b ^ ((sub & 7) << 4);
    const char* gb = (const char*)(g + k0) + (size_t)sub * (size_t)(ld * 2) + bs;
    char* lb = lds + ((t >> 6) << 10);
    const size_t rstep = (size_t)32 * (ld * 2);
#pragma unroll
    for (int r = 0; r < 4; ++r)
        gload_lds16(gb + r * rstep, lb + r * 4096);
}

// ---- one 128x128x64 MFMA step (normal orientation: D row <- A-op(As)) ----
DEV void mfma_tile(const char* As, const char* Bs, int lane, int wr, int wc, frag_cd (&acc)[4][4]) {
#pragma unroll
    for (int ks = 0; ks < 2; ++ks) {
        const int boff = ks * 64 + ((lane >> 4) << 4);
        frag_ab av[4];
#pragma unroll
        for (int f = 0; f < 4; ++f) {
            int ra = wr * 64 + f * 16 + (lane & 15);
            av[f] = *(const frag_ab*)(As + ra * 128 + (boff ^ ((ra & 7) << 4)));
        }
#pragma unroll
        for (int j = 0; j < 4; ++j) {
            int rb = wc * 64 + j * 16 + (lane & 15);
            frag_ab bv = *(const frag_ab*)(Bs + rb * 128 + (boff ^ ((rb & 7) << 4)));
#pragma unroll
            for (int i = 0; i < 4; ++i)
                acc[i][j] = __builtin_amdgcn_mfma_f32_16x16x32_bf16(av[i], bv, acc[i][j], 0, 0, 0);
        }
    }
}

// ---- swapped-operand variant: acc[i][j] = mfma(et_frag(j), eh_frag(i)) = S^T tile.
// Lane holds, per i: eh row = wr*64+i*16+(lane&15); et cols j*16+(lane>>4)*4+r.
DEV void mfma_tile_swp(const char* As, const char* Bs, int lane, int wr, int wc, frag_cd (&acc)[4][4]) {
#pragma unroll
    for (int ks = 0; ks < 2; ++ks) {
        const int boff = ks * 64 + ((lane >> 4) << 4);
        frag_ab av[4];
#pragma unroll
        for (int f = 0; f < 4; ++f) {
            int ra = wr * 64 + f * 16 + (lane & 15);
            av[f] = *(const frag_ab*)(As + ra * 128 + (boff ^ ((ra & 7) << 4)));
        }
#pragma unroll
        for (int j = 0; j < 4; ++j) {
            int rb = wc * 64 + j * 16 + (lane & 15);
            frag_ab bv = *(const frag_ab*)(Bs + rb * 128 + (boff ^ ((rb & 7) << 4)));
#pragma unroll
            for (int i = 0; i < 4; ++i)
                acc[i][j] = __builtin_amdgcn_mfma_f32_16x16x32_bf16(bv, av[i], acc[i][j], 0, 0, 0);
        }
    }
}

// ---- generic bf16 GEMM, 2-stage software pipeline (static buffers, unroll 1);
// blockIdx.z selects job. C = act(A @ BT^T + bias); EPI: 0=store, 1=store+colsum, 2=colsum only ----
template <int ACT, int EPI>
__global__ __launch_bounds__(256, 2) void k_gemm(
    const unsigned short* __restrict__ A0, const unsigned short* __restrict__ A1,
    const unsigned short* __restrict__ B0, const unsigned short* __restrict__ B1,
    const float* __restrict__ bias0, const float* __restrict__ bias1,
    unsigned short* __restrict__ out0, unsigned short* __restrict__ out1,
    float* __restrict__ colsum, int M, int N, int K) {
    __shared__ __align__(16) char smem[65536];
    __shared__ float colacc[128];
    char* sA0 = smem;
    char* sA1 = smem + 16384;
    char* sB0 = smem + 32768;
    char* sB1 = smem + 49152;
    const int z = blockIdx.z;
    const unsigned short* A = z ? A1 : A0;
    const unsigned short* BT = z ? B1 : B0;
    const float* bias = z ? bias1 : bias0;
    unsigned short* out = z ? out1 : out0;
    const int t = threadIdx.x;
    const int lane = t & 63, wid = t >> 6, wr = wid >> 1, wc = wid & 1;
    const int m0 = blockIdx.x * 128, n0 = blockIdx.y * 128;
    if (EPI >= 1 && t < 128) colacc[t] = 0.f;
    const unsigned short* Ap = A + (size_t)m0 * K;
    const unsigned short* Bp = BT + (size_t)n0 * K;
    frag_cd acc[4][4] = {};
    const int nt = K >> 6;  // even, >= 4
    stage_async(Ap, K, 0, sA0, t);
    stage_async(Bp, K, 0, sB0, t);
    __syncthreads();
#pragma unroll 1
    for (int tt = 0; tt < nt - 2; tt += 2) {
        stage_async(Ap, K, (tt + 1) * 64, sA1, t);
        stage_async(Bp, K, (tt + 1) * 64, sB1, t);
        mfma_tile(sA0, sB0, lane, wr, wc, acc);
        __syncthreads();
        stage_async(Ap, K, (tt + 2) * 64, sA0, t);
        stage_async(Bp, K, (tt + 2) * 64, sB0, t);
        mfma_tile(sA1, sB1, lane, wr, wc, acc);
        __syncthreads();
    }
    stage_async(Ap, K, (nt - 1) * 64, sA1, t);
    stage_async(Bp, K, (nt - 1) * 64, sB1, t);
    mfma_tile(sA0, sB0, lane, wr, wc, acc);
    __syncthreads();
    mfma_tile(sA1, sB1, lane, wr, wc, acc);
    // epilogue
    float bval[4];
#pragma unroll
    for (int j = 0; j < 4; ++j) bval[j] = bias[n0 + wc * 64 + j * 16 + (lane & 15)];
#pragma unroll
    for (int i = 0; i < 4; ++i) {
#pragma unroll
        for (int j = 0; j < 4; ++j) {
            float cs = 0.f;
#pragma unroll
            for (int r = 0; r < 4; ++r) {
                float v = acc[i][j][r] + bval[j];
                if (ACT) v = v > 0.f ? v : 0.01f * v;
                if (EPI != 2) {
                    int row = m0 + wr * 64 + i * 16 + (lane >> 4) * 4 + r;
                    int col = n0 + wc * 64 + j * 16 + (lane & 15);
                    out[(size_t)row * N + col] = f2bf(v);
                }
                cs += v;
            }
            if (EPI >= 1) atomicAdd(&colacc[wc * 64 + j * 16 + (lane & 15)], cs);
        }
    }
    if (EPI >= 1) {
        __syncthreads();
        if (t < 128) atomicAdd(&colsum[n0 + t], colacc[t]);
    }
}

// ---- sorted-desc top-6 key insert via med3 (6 ops, dep depth 1):
// v[0]'=max(v0,k); v[j]'=med3(v[j-1]_old, v[j], k)  [proof in journal] ----
DEV unsigned med3u(unsigned a, unsigned b, unsigned c) {
    unsigned r;
    asm("v_med3_u32 %0, %1, %2, %3" : "=v"(r) : "v"(a), "v"(b), "v"(c));
    return r;
}
DEV void kins(unsigned (&v)[6], unsigned k) {
    unsigned t0 = v[0], t1 = v[1], t2 = v[2], t3 = v[3], t4 = v[4];
    v[0] = v[0] > k ? v[0] : k;
    v[1] = med3u(t0, v[1], k);
    v[2] = med3u(t1, v[2], k);
    v[3] = med3u(t2, v[3], k);
    v[4] = med3u(t3, v[4], k);
    v[5] = med3u(t4, v[5], k);
}

// ---- fused attn-logit GEMM + fully in-register top-6 (swapped-operand S^T) ----
// grid (64 row-blocks, 16 col-splits); block = 128 rows x 512 cols, 256 thr.
__global__ __launch_bounds__(256, 2) void k_attn_topk(
    const unsigned short* __restrict__ ehb, const unsigned short* __restrict__ etb,
    unsigned* __restrict__ pk) {
    __shared__ __align__(16) char smem[65536];
    char* sA0 = smem;
    char* sA1 = smem + 16384;
    char* sB0 = smem + 32768;
    char* sB1 = smem + 49152;
    unsigned* xbuf = (unsigned*)smem;  // [128][6] cross-wave merge buf (3KB), used once at end
    const int t = threadIdx.x;
    const int lane = t & 63, wid = t >> 6, wr = wid >> 1, wc = wid & 1;
    const int m0 = blockIdx.x * 128;
    const int csplit = blockIdx.y;
    const unsigned short* Ap = ehb + (size_t)m0 * 512;
    unsigned kl[4][6] = {};  // per-row top-6 key lists (key 0 < any real key)

    // prologue: stage ct=0, k=0
    stage_async(Ap, 512, 0, sA0, t);
    stage_async(etb + (size_t)(csplit * 512) * 512, 512, 0, sB0, t);

#pragma unroll 1
    for (int ct = 0; ct < 4; ++ct) {
        const int n0 = csplit * 512 + ct * 128;
        const unsigned short* Bp = etb + (size_t)n0 * 512;
        frag_cd acc[4][4] = {};
        __syncthreads();  // drains prologue/tail stage of this ct
#pragma unroll 1
        for (int p = 0; p < 3; ++p) {
            stage_async(Ap, 512, (2 * p + 1) * 64, sA1, t);
            stage_async(Bp, 512, (2 * p + 1) * 64, sB1, t);
            __builtin_amdgcn_s_setprio(1);
            mfma_tile_swp(sA0, sB0, lane, wr, wc, acc);
            __builtin_amdgcn_s_setprio(0);
            __syncthreads();
            stage_async(Ap, 512, (2 * p + 2) * 64, sA0, t);
            stage_async(Bp, 512, (2 * p + 2) * 64, sB0, t);
            __builtin_amdgcn_s_setprio(1);
            mfma_tile_swp(sA1, sB1, lane, wr, wc, acc);
            __builtin_amdgcn_s_setprio(0);
            __syncthreads();
        }
        stage_async(Ap, 512, 7 * 64, sA1, t);
        stage_async(Bp, 512, 7 * 64, sB1, t);
        __builtin_amdgcn_s_setprio(1);
        mfma_tile_swp(sA0, sB0, lane, wr, wc, acc);
        __builtin_amdgcn_s_setprio(0);
        __syncthreads();
        if (ct < 3) {  // tail: stage next ct's k=0 into sA0/sB0 (disjoint from sA1/sB1)
            stage_async(Ap, 512, 0, sA0, t);
            stage_async(etb + (size_t)(n0 + 128) * 512, 512, 0, sB0, t);
        }
        __builtin_amdgcn_s_setprio(1);
        mfma_tile_swp(sA1, sB1, lane, wr, wc, acc);
        __builtin_amdgcn_s_setprio(0);
        // in-register scan of this ct's S^T tile (overlaps the tail stage's latency)
        const int base_ck = 8191 - (n0 + wc * 64 + ((lane >> 4) << 2));
#pragma unroll
        for (int i = 0; i < 4; ++i)
#pragma unroll
            for (int j = 0; j < 4; ++j)
#pragma unroll
                for (int r = 0; r < 4; ++r) {
                    unsigned key = (mono(acc[i][j][r]) & 0xFFFFE000u) |
                                   (unsigned)(base_ck - j * 16 - r);
                    kins(kl[i], key);
                }
    }
    // merge across lane>>4 groups (same eh row, disjoint et cols): xor 16 then 32
#pragma unroll
    for (int i = 0; i < 4; ++i) {
#pragma unroll
        for (int j = 0; j < 6; ++j) {
            unsigned ok = (unsigned)__shfl_xor((int)kl[i][j], 16, 64);
            kins(kl[i], ok);
        }
#pragma unroll
        for (int j = 0; j < 6; ++j) {
            unsigned ok = (unsigned)__shfl_xor((int)kl[i][j], 32, 64);
            kins(kl[i], ok);
        }
    }
    // cross-wave (wc) merge via small LDS buffer
    __syncthreads();  // all GEMM reads done; smem reusable
    if (wc == 1 && (lane >> 4) == 0) {
#pragma unroll
        for (int i = 0; i < 4; ++i) {
            int row = wr * 64 + i * 16 + lane;
#pragma unroll
            for (int j = 0; j < 6; ++j) xbuf[row * 6 + j] = kl[i][j];
        }
    }
    __syncthreads();
    if (wc == 0 && (lane >> 4) == 0) {
#pragma unroll
        for (int i = 0; i < 4; ++i) {
            int row = wr * 64 + i * 16 + lane;
#pragma unroll
            for (int j = 0; j < 6; ++j) kins(kl[i], xbuf[row * 6 + j]);
            size_t o = ((size_t)(m0 + row) * 16 + csplit) * 6;
#pragma unroll
            for (int j = 0; j < 6; ++j) pk[o + j] = kl[i][j];
        }
    }
}

// ---- merge 16 partial top-6 key lists -> final top-6 per row; decode ----
__global__ void k_merge_topk(const unsigned* __restrict__ pk,
                             float* __restrict__ tw, int* __restrict__ ti) {
    int r = blockIdx.x * 256 + threadIdx.x;
    if (r >= 8192) return;
    unsigned v[6] = {0, 0, 0, 0, 0, 0};
    for (int s2 = 0; s2 < 16; ++s2) {
        const unsigned* p = pk + ((size_t)r * 16 + s2) * 6;
#pragma unroll
        for (int j = 0; j < 6; ++j) kins(v, p[j]);
    }
#pragma unroll
    for (int j = 0; j < 6; ++j) {
        tw[r * 6 + j] = unmono(v[j] & 0xFFFFE000u) * SCALE_C;
        ti[r * 6 + j] = 8191 - (int)(v[j] & 8191u);
    }
}

// ---- fast tanh: 1 - 2/(e^{2x}+1); exact at +/-inf, ~1e-6 abs err ----
DEV float ftanh(float x) {
    float t = __expf(2.f * x);
    return 1.f - 2.f * __builtin_amdgcn_rcpf(t + 1.f);
}

// ---- per-node neighbor aggregation: one wave per node ----
__global__ __launch_bounds__(256) void k_agg(
    const unsigned short* __restrict__ ehb, const unsigned short* __restrict__ etb,
    const float* __restrict__ tw, const int* __restrict__ ti,
    unsigned short* __restrict__ sb, unsigned short* __restrict__ pb) {
    const int t = threadIdx.x, lane = t & 63, wid = t >> 6;
    const int node = blockIdx.x * 4 + wid;
    const int d0 = lane * 8;
    float w[6]; int idx[6];
#pragma unroll
    for (int k = 0; k < 6; ++k) { w[k] = tw[node * 6 + k]; idx[k] = ti[node * 6 + k]; }
    float mx = w[0];
#pragma unroll
    for (int k = 1; k < 6; ++k) mx = fmaxf(mx, w[k]);
    float pr[6], s = 0.f;
#pragma unroll
    for (int k = 0; k < 6; ++k) { pr[k] = __expf(w[k] - mx); s += pr[k]; }
    float inv = 1.f / s;
#pragma unroll
    for (int k = 0; k < 6; ++k) pr[k] *= inv;

    float eh[8]; unpack8(*(const uint4*)(ehb + (size_t)node * 512 + d0), eh);
    float nb[6][8];
#pragma unroll
    for (int k = 0; k < 6; ++k) unpack8(*(const uint4*)(etb + (size_t)idx[k] * 512 + d0), nb[k]);

    float kw[6] = {};
#pragma unroll
    for (int k = 0; k < 6; ++k) {
        float pk2 = pr[k];
#pragma unroll
        for (int j = 0; j < 8; ++j) {
            float ehr = pk2 * nb[k][j] + (1.f - pk2) * eh[j];
            float g = ftanh(eh[j] + ehr);
            kw[k] += nb[k][j] * g;
        }
    }
#pragma unroll
    for (int k = 0; k < 6; ++k)
#pragma unroll
        for (int o = 1; o < 64; o <<= 1) kw[k] += __shfl_xor(kw[k], o, 64);
    float m2 = kw[0];
#pragma unroll
    for (int k = 1; k < 6; ++k) m2 = fmaxf(m2, kw[k]);
    float kp[6], s2 = 0.f;
#pragma unroll
    for (int k = 0; k < 6; ++k) { kp[k] = __expf(kw[k] - m2); s2 += kp[k]; }
    float inv2 = 1.f / s2;
#pragma unroll
    for (int k = 0; k < 6; ++k) kp[k] *= inv2;

    float sv[8], pv[8];
#pragma unroll
    for (int j = 0; j < 8; ++j) {
        float en = 0.f;
#pragma unroll
        for (int k = 0; k < 6; ++k) en += kp[k] * nb[k][j];
        sv[j] = eh[j] + en;
        pv[j] = eh[j] * en;
    }
    *(uint4*)(sb + (size_t)node * 512 + d0) = pack8(sv);
    *(uint4*)(pb + (size_t)node * 512 + d0) = pack8(pv);
}

// ---- final: node-mean -> LN -> classifier ----
DEV float blocksum512(float v, float* red, int lane, int wid) {
#pragma unroll
    for (int o = 1; o < 64; o <<= 1) v += __shfl_xor(v, o, 64);
    __syncthreads();
    if (lane == 0) red[wid] = v;
    __syncthreads();
    float s = 0.f;
#pragma unroll
    for (int w2 = 0; w2 < 8; ++w2) s += red[w2];
    return s;
}

__global__ __launch_bounds__(512) void k_final(
    const float* __restrict__ colsum_emb, const float* __restrict__ ln_g,
    const float* __restrict__ ln_b, const float* __restrict__ cls_w,
    const float* __restrict__ cls_b, float* __restrict__ out) {
    __shared__ float red[8];
    const int t = threadIdx.x, lane = t & 63, wid = t >> 6;
    float h = colsum_emb[t] * (1.f / 8192.f);
    float mu = blocksum512(h, red, lane, wid) * (1.f / 512.f);
    float d = h - mu;
    float var = blocksum512(d * d, red, lane, wid) * (1.f / 512.f);
    float y = d * rsqrtf(var + 1e-5f) * ln_g[t] + ln_b[t];
    float s0 = blocksum512(y * cls_w[t * 2 + 0], red, lane, wid);
    float s1 = blocksum512(y * cls_w[t * 2 + 1], red, lane, wid);
    if (t == 0) { out[0] = s0 + cls_b[0]; out[1] = s1 + cls_b[1]; }
}

extern "C" void kernel_launch(void* const* d_in, const int* in_sizes, int n_in,
                              void* d_out, int out_size, void* d_ws, size_t ws_size,
                              hipStream_t stream) {
    (void)in_sizes; (void)n_in; (void)out_size; (void)ws_size;
    const float* feats = (const float*)d_in[0];
    const float* fc1_w = (const float*)d_in[1];
    const float* fc1_b = (const float*)d_in[2];
    const float* wh_w  = (const float*)d_in[3];
    const float* wh_b  = (const float*)d_in[4];
    const float* wt_w  = (const float*)d_in[5];
    const float* wt_b  = (const float*)d_in[6];
    const float* l1_w  = (const float*)d_in[7];
    const float* l1_b  = (const float*)d_in[8];
    const float* l2_w  = (const float*)d_in[9];
    const float* l2_b  = (const float*)d_in[10];
    const float* ln_g  = (const float*)d_in[11];
    const float* ln_b  = (const float*)d_in[12];
    const float* cls_w = (const float*)d_in[13];
    const float* cls_b = (const float*)d_in[14];

    char* ws = (char*)d_ws;
    size_t off = 0;
    auto alloc = [&](size_t bytes) {
        char* p = ws + off;
        off += (bytes + 255) & ~(size_t)255;
        return p;
    };
    unsigned short* fb   = (unsigned short*)alloc(8192ull * 384 * 2);
    unsigned short* xb   = (unsigned short*)alloc(8192ull * 512 * 2);
    unsigned short* ehb  = (unsigned short*)alloc(8192ull * 512 * 2);
    unsigned short* etb  = (unsigned short*)alloc(8192ull * 512 * 2);
    unsigned short* sb   = (unsigned short*)alloc(8192ull * 512 * 2);
    unsigned short* pb   = (unsigned short*)alloc(8192ull * 512 * 2);
    unsigned short* wfc1T = (unsigned short*)alloc(512ull * 384 * 2);
    unsigned short* whT  = (unsigned short*)alloc(512ull * 512 * 2);
    unsigned short* wtT  = (unsigned short*)alloc(512ull * 512 * 2);
    unsigned short* l1T  = (unsigned short*)alloc(512ull * 512 * 2);
    unsigned short* l2T  = (unsigned short*)alloc(512ull * 512 * 2);
    float* colsum     = (float*)alloc(512 * 4);
    float* colsum_emb = (float*)alloc(512 * 4);
    float* cvh = (float*)alloc(512 * 4);
    float* cvt = (float*)alloc(512 * 4);
    unsigned* pk = (unsigned*)alloc(8192ull * 16 * 6 * 4);
    float* tw = (float*)alloc(8192ull * 6 * 4);
    int*   ti = (int*)alloc(8192ull * 6 * 4);

    hipMemsetAsync(colsum, 0, 512 * 4, stream);
    hipMemsetAsync(colsum_emb, 0, 512 * 4, stream);

    // fused conv + 5 LDS-tiled weight transposes (wh/wt scaled 0.5)
    k_prep<<<dim3(256, 1, 6), 256, 0, stream>>>(
        feats, fc1_w, wh_w, wt_w, l1_w, l2_w, fb, wfc1T, whT, wtT, l1T, l2T);

    // x0 = lrelu(feats@fc1 + b), colsum(x0)  [xb holds x0; mean folded into bias below]
    k_gemm<1, 1><<<dim3(64, 4, 1), 256, 0, stream>>>(
        fb, fb, wfc1T, wfc1T, fc1_b, fc1_b, xb, xb, colsum, 8192, 512, 384);
    // rank-1 fold: cv = b + 0.5*colmean@W (f32)
    k_rank1<<<2, 512, 0, stream>>>(colsum, wh_w, wt_w, wh_b, wt_b, cvh, cvt);
    // e_h and e_t in one dual launch: e = x0 @ (0.5W) + cv
    k_gemm<0, 0><<<dim3(64, 4, 2), 256, 0, stream>>>(
        xb, xb, whT, wtT, cvh, cvt, ehb, etb, nullptr, 8192, 512, 512);
    // attn logits + fused in-register top-6 (128x128 tiles, 16 col-splits), then merge+decode
    k_attn_topk<<<dim3(64, 16), 256, 0, stream>>>(ehb, etb, pk);
    k_merge_topk<<<32, 256, 0, stream>>>(pk, tw, ti);
    // neighbor aggregation -> s = e_h + e_Nh, p = e_h * e_Nh (bf16)
    k_agg<<<2048, 256, 0, stream>>>(ehb, etb, tw, ti, sb, pb);
    // emb colsums in one dual launch (never materialize emb)
    k_gemm<1, 2><<<dim3(64, 4, 2), 256, 0, stream>>>(
        sb, pb, l1T, l2T, l1_b, l2_b, nullptr, nullptr, colsum_emb, 8192, 512, 512);
    // mean -> LN -> classifier
    k_final<<<1, 512, 0, stream>>>(colsum_emb, ln_g, ln_b, cls_w, cls_b, (float*)d_out);
}

// Round 11
// 168.548 us; speedup vs baseline: 1.1349x; 1.1349x over previous
//
#include <hip/hip_runtime.h>
#include <math.h>

#define DEV __device__ __forceinline__

// ---- MFMA fragment types (gfx950 16x16x32 bf16) ----
using frag_ab = __attribute__((ext_vector_type(8))) short;  // 8 bf16 (4 VGPRs)
using frag_cd = __attribute__((ext_vector_type(4))) float;  // 4 fp32

static constexpr float SCALE_C = 0.04419417382415922f;  // 512^-0.5

// ---- bf16 helpers (RNE) ----
DEV unsigned short f2bf(float f) {
    unsigned u = __float_as_uint(f);
    unsigned r = (u + 0x7FFFu + ((u >> 16) & 1u)) >> 16;
    return (unsigned short)r;
}
DEV float bf2f(unsigned short h) { return __uint_as_float(((unsigned)h) << 16); }

DEV void unpack8(uint4 q, float f[8]) {
    f[0] = bf2f((unsigned short)(q.x & 0xFFFFu)); f[1] = bf2f((unsigned short)(q.x >> 16));
    f[2] = bf2f((unsigned short)(q.y & 0xFFFFu)); f[3] = bf2f((unsigned short)(q.y >> 16));
    f[4] = bf2f((unsigned short)(q.z & 0xFFFFu)); f[5] = bf2f((unsigned short)(q.z >> 16));
    f[6] = bf2f((unsigned short)(q.w & 0xFFFFu)); f[7] = bf2f((unsigned short)(q.w >> 16));
}
DEV uint4 pack8(const float f[8]) {
    uint4 q;
    q.x = (unsigned)f2bf(f[0]) | ((unsigned)f2bf(f[1]) << 16);
    q.y = (unsigned)f2bf(f[2]) | ((unsigned)f2bf(f[3]) << 16);
    q.z = (unsigned)f2bf(f[4]) | ((unsigned)f2bf(f[5]) << 16);
    q.w = (unsigned)f2bf(f[6]) | ((unsigned)f2bf(f[7]) << 16);
    return q;
}

// ---- order-preserving float<->u32 (monotone key) ----
DEV unsigned mono(float f) {
    unsigned u = __float_as_uint(f);
    return u ^ ((unsigned)((int)u >> 31) | 0x80000000u);
}
DEV float unmono(unsigned k) {
    unsigned u = (k & 0x80000000u) ? (k & 0x7FFFFFFFu) : ~k;
    return __uint_as_float(u);
}

// ---- async global->LDS 16B (direct-to-LDS DMA; dest = wave base + lane*16) ----
DEV void gload_lds16(const void* g, void* l) {
    __builtin_amdgcn_global_load_lds(
        (const __attribute__((address_space(1))) void*)g,
        (__attribute__((address_space(3))) void*)l, 16, 0, 0);
}

// ---- fused prep: z=0..4 LDS-tiled weight transposes ([K][512]f32 -> [512][K]bf16,
// wh/wt scaled by 0.5 for the rank-1 mean fold), z=5 feats conv ----
__global__ void k_prep(const float* __restrict__ feats, const float* __restrict__ fc1_w,
                       const float* __restrict__ wh_w, const float* __restrict__ wt_w,
                       const float* __restrict__ l1_w, const float* __restrict__ l2_w,
                       unsigned short* __restrict__ fb, unsigned short* __restrict__ wfc1T,
                       unsigned short* __restrict__ whT, unsigned short* __restrict__ wtT,
                       unsigned short* __restrict__ l1T, unsigned short* __restrict__ l2T) {
    const int z = blockIdx.z;
    const int tid = threadIdx.x;
    if (z == 5) {  // conv feats f32 -> bf16, grid-stride
        for (int i = (blockIdx.x * 256 + tid) * 4; i < 8192 * 384; i += 256 * 256 * 4) {
            float4 v = *(const float4*)(feats + i);
            ushort4 o;
            o.x = f2bf(v.x); o.y = f2bf(v.y); o.z = f2bf(v.z); o.w = f2bf(v.w);
            *(ushort4*)(fb + i) = o;
        }
        return;
    }
    const float* s = z == 0 ? fc1_w : z == 1 ? wh_w : z == 2 ? wt_w : z == 3 ? l1_w : l2_w;
    unsigned short* d = z == 0 ? wfc1T : z == 1 ? whT : z == 2 ? wtT : z == 3 ? l1T : l2T;
    const int K = z == 0 ? 384 : 512;
    const float scale = (z == 1 || z == 2) ? 0.5f : 1.0f;
    const int ntk = K >> 6;
    const int t = blockIdx.x;
    if (t >= ntk * 8) return;
    const int k0 = (t % ntk) * 64, n0 = (t / ntk) * 64;
    __shared__ short tile[64 * 68];  // [n][k], stride 68
    // phase 1: coalesced f32 read, transposed bf16 scatter into LDS
#pragma unroll
    for (int p = 0; p < 4; ++p) {
        int kk = p * 16 + (tid >> 4);
        int nn = (tid & 15) * 4;
        float4 v = *(const float4*)(s + (size_t)(k0 + kk) * 512 + n0 + nn);
        tile[(nn + 0) * 68 + kk] = (short)f2bf(v.x * scale);
        tile[(nn + 1) * 68 + kk] = (short)f2bf(v.y * scale);
        tile[(nn + 2) * 68 + kk] = (short)f2bf(v.z * scale);
        tile[(nn + 3) * 68 + kk] = (short)f2bf(v.w * scale);
    }
    __syncthreads();
    // phase 2: row reads from LDS, coalesced 16B global stores
#pragma unroll
    for (int p = 0; p < 2; ++p) {
        int rr = p * 32 + (tid >> 3);
        int cc = (tid & 7) * 8;
        const short* rp = &tile[rr * 68 + cc];
        uint2 a = *(const uint2*)(rp);
        uint2 b = *(const uint2*)(rp + 4);
        uint4 o = {a.x, a.y, b.x, b.y};
        *(uint4*)(d + (size_t)(n0 + rr) * K + k0 + cc) = o;
    }
}

// ---- rank-1 mean fold: cv[n] = b[n] + (1/8192) * <colsum, whT_row_n>
// (whT holds 0.5*W in bf16, L2-hot; one wave per output n, coalesced 1KB row read) ----
__global__ __launch_bounds__(512) void k_rank1(
    const float* __restrict__ colsum,
    const unsigned short* __restrict__ whT, const unsigned short* __restrict__ wtT,
    const float* __restrict__ wh_b, const float* __restrict__ wt_b,
    float* __restrict__ cvh, float* __restrict__ cvt) {
    const int lane = threadIdx.x & 63, wid = threadIdx.x >> 6;
    const int n = blockIdx.x * 8 + wid;  // 64 blocks x 8 waves = 512 outputs
    const unsigned short* W = blockIdx.y ? wtT : whT;
    const float* b = blockIdx.y ? wt_b : wh_b;
    float* cv = blockIdx.y ? cvt : cvh;
    float f[8];
    unpack8(*(const uint4*)(W + (size_t)n * 512 + lane * 8), f);
    float4 c0 = *(const float4*)(colsum + lane * 8);
    float4 c1 = *(const float4*)(colsum + lane * 8 + 4);
    float s = f[0] * c0.x + f[1] * c0.y + f[2] * c0.z + f[3] * c0.w +
              f[4] * c1.x + f[5] * c1.y + f[6] * c1.z + f[7] * c1.w;
#pragma unroll
    for (int o = 1; o < 64; o <<= 1) s += __shfl_xor(s, o, 64);
    if (lane == 0) cv[n] = b[n] + s * (1.f / 8192.f);
}

// ---- staging: 128 rows x 64 bf16 (16KB), XOR-swizzled source, linear LDS dest ----
DEV void stage_async(const unsigned short* __restrict__ g, int ld, int k0, char* lds, int t) {
    const int sub = t >> 3;
    const int b = (t & 7) << 4;
    const int bs = b ^ ((sub & 7) << 4);
    const char* gb = (const char*)(g + k0) + (size_t)sub * (size_t)(ld * 2) + bs;
    char* lb = lds + ((t >> 6) << 10);
    const size_t rstep = (size_t)32 * (ld * 2);
#pragma unroll
    for (int r = 0; r < 4; ++r)
        gload_lds16(gb + r * rstep, lb + r * 4096);
}

// ---- one 128x128x64 MFMA step (normal orientation: D row <- A-op(As)) ----
DEV void mfma_tile(const char* As, const char* Bs, int lane, int wr, int wc, frag_cd (&acc)[4][4]) {
#pragma unroll
    for (int ks = 0; ks < 2; ++ks) {
        const int boff = ks * 64 + ((lane >> 4) << 4);
        frag_ab av[4];
#pragma unroll
        for (int f = 0; f < 4; ++f) {
            int ra = wr * 64 + f * 16 + (lane & 15);
            av[f] = *(const frag_ab*)(As + ra * 128 + (boff ^ ((ra & 7) << 4)));
        }
#pragma unroll
        for (int j = 0; j < 4; ++j) {
            int rb = wc * 64 + j * 16 + (lane & 15);
            frag_ab bv = *(const frag_ab*)(Bs + rb * 128 + (boff ^ ((rb & 7) << 4)));
#pragma unroll
            for (int i = 0; i < 4; ++i)
                acc[i][j] = __builtin_amdgcn_mfma_f32_16x16x32_bf16(av[i], bv, acc[i][j], 0, 0, 0);
        }
    }
}

// ---- swapped-operand variant: acc[i][j] = mfma(et_frag(j), eh_frag(i)) = S^T tile.
// Lane holds, per i: eh row = wr*64+i*16+(lane&15); et cols j*16+(lane>>4)*4+r.
DEV void mfma_tile_swp(const char* As, const char* Bs, int lane, int wr, int wc, frag_cd (&acc)[4][4]) {
#pragma unroll
    for (int ks = 0; ks < 2; ++ks) {
        const int boff = ks * 64 + ((lane >> 4) << 4);
        frag_ab av[4];
#pragma unroll
        for (int f = 0; f < 4; ++f) {
            int ra = wr * 64 + f * 16 + (lane & 15);
            av[f] = *(const frag_ab*)(As + ra * 128 + (boff ^ ((ra & 7) << 4)));
        }
#pragma unroll
        for (int j = 0; j < 4; ++j) {
            int rb = wc * 64 + j * 16 + (lane & 15);
            frag_ab bv = *(const frag_ab*)(Bs + rb * 128 + (boff ^ ((rb & 7) << 4)));
#pragma unroll
            for (int i = 0; i < 4; ++i)
                acc[i][j] = __builtin_amdgcn_mfma_f32_16x16x32_bf16(bv, av[i], acc[i][j], 0, 0, 0);
        }
    }
}

// ---- generic bf16 GEMM, 2-stage software pipeline (static buffers, unroll 1);
// blockIdx.z selects job. C = act(A @ BT^T + bias); EPI: 0=store, 1=store+colsum, 2=colsum only ----
template <int ACT, int EPI>
__global__ __launch_bounds__(256, 2) void k_gemm(
    const unsigned short* __restrict__ A0, const unsigned short* __restrict__ A1,
    const unsigned short* __restrict__ B0, const unsigned short* __restrict__ B1,
    const float* __restrict__ bias0, const float* __restrict__ bias1,
    unsigned short* __restrict__ out0, unsigned short* __restrict__ out1,
    float* __restrict__ colsum, int M, int N, int K) {
    __shared__ __align__(16) char smem[65536];
    __shared__ float colacc[128];
    char* sA0 = smem;
    char* sA1 = smem + 16384;
    char* sB0 = smem + 32768;
    char* sB1 = smem + 49152;
    const int z = blockIdx.z;
    const unsigned short* A = z ? A1 : A0;
    const unsigned short* BT = z ? B1 : B0;
    const float* bias = z ? bias1 : bias0;
    unsigned short* out = z ? out1 : out0;
    const int t = threadIdx.x;
    const int lane = t & 63, wid = t >> 6, wr = wid >> 1, wc = wid & 1;
    const int m0 = blockIdx.x * 128, n0 = blockIdx.y * 128;
    if (EPI >= 1 && t < 128) colacc[t] = 0.f;
    const unsigned short* Ap = A + (size_t)m0 * K;
    const unsigned short* Bp = BT + (size_t)n0 * K;
    frag_cd acc[4][4] = {};
    const int nt = K >> 6;  // even, >= 4
    stage_async(Ap, K, 0, sA0, t);
    stage_async(Bp, K, 0, sB0, t);
    __syncthreads();
#pragma unroll 1
    for (int tt = 0; tt < nt - 2; tt += 2) {
        stage_async(Ap, K, (tt + 1) * 64, sA1, t);
        stage_async(Bp, K, (tt + 1) * 64, sB1, t);
        mfma_tile(sA0, sB0, lane, wr, wc, acc);
        __syncthreads();
        stage_async(Ap, K, (tt + 2) * 64, sA0, t);
        stage_async(Bp, K, (tt + 2) * 64, sB0, t);
        mfma_tile(sA1, sB1, lane, wr, wc, acc);
        __syncthreads();
    }
    stage_async(Ap, K, (nt - 1) * 64, sA1, t);
    stage_async(Bp, K, (nt - 1) * 64, sB1, t);
    mfma_tile(sA0, sB0, lane, wr, wc, acc);
    __syncthreads();
    mfma_tile(sA1, sB1, lane, wr, wc, acc);
    // epilogue
    float bval[4];
#pragma unroll
    for (int j = 0; j < 4; ++j) bval[j] = bias[n0 + wc * 64 + j * 16 + (lane & 15)];
#pragma unroll
    for (int i = 0; i < 4; ++i) {
#pragma unroll
        for (int j = 0; j < 4; ++j) {
            float cs = 0.f;
#pragma unroll
            for (int r = 0; r < 4; ++r) {
                float v = acc[i][j][r] + bval[j];
                if (ACT) v = v > 0.f ? v : 0.01f * v;
                if (EPI != 2) {
                    int row = m0 + wr * 64 + i * 16 + (lane >> 4) * 4 + r;
                    int col = n0 + wc * 64 + j * 16 + (lane & 15);
                    out[(size_t)row * N + col] = f2bf(v);
                }
                cs += v;
            }
            if (EPI >= 1) atomicAdd(&colacc[wc * 64 + j * 16 + (lane & 15)], cs);
        }
    }
    if (EPI >= 1) {
        __syncthreads();
        if (t < 128) atomicAdd(&colsum[n0 + t], colacc[t]);
    }
}

// ---- sorted-desc top-6 key insert via med3 (6 ops, dep depth 1):
// v[0]'=max(v0,k); v[j]'=med3(v[j-1]_old, v[j], k) ----
DEV unsigned med3u(unsigned a, unsigned b, unsigned c) {
    unsigned r;
    asm("v_med3_u32 %0, %1, %2, %3" : "=v"(r) : "v"(a), "v"(b), "v"(c));
    return r;
}
DEV void kins(unsigned (&v)[6], unsigned k) {
    unsigned t0 = v[0], t1 = v[1], t2 = v[2], t3 = v[3], t4 = v[4];
    v[0] = v[0] > k ? v[0] : k;
    v[1] = med3u(t0, v[1], k);
    v[2] = med3u(t1, v[2], k);
    v[3] = med3u(t2, v[3], k);
    v[4] = med3u(t3, v[4], k);
    v[5] = med3u(t4, v[5], k);
}

// ---- fused attn-logit GEMM + fully in-register top-6 (swapped-operand S^T) ----
// grid (64 row-blocks, 16 col-splits); block = 128 rows x 512 cols, 256 thr.
__global__ __launch_bounds__(256, 2) void k_attn_topk(
    const unsigned short* __restrict__ ehb, const unsigned short* __restrict__ etb,
    unsigned* __restrict__ pk) {
    __shared__ __align__(16) char smem[65536];
    char* sA0 = smem;
    char* sA1 = smem + 16384;
    char* sB0 = smem + 32768;
    char* sB1 = smem + 49152;
    unsigned* xbuf = (unsigned*)smem;  // [128][6] cross-wave merge buf (3KB), used once at end
    const int t = threadIdx.x;
    const int lane = t & 63, wid = t >> 6, wr = wid >> 1, wc = wid & 1;
    const int m0 = blockIdx.x * 128;
    const int csplit = blockIdx.y;
    const unsigned short* Ap = ehb + (size_t)m0 * 512;
    unsigned kl[4][6] = {};  // per-row top-6 key lists (key 0 < any real key)

    // prologue: stage ct=0, k=0
    stage_async(Ap, 512, 0, sA0, t);
    stage_async(etb + (size_t)(csplit * 512) * 512, 512, 0, sB0, t);

#pragma unroll 1
    for (int ct = 0; ct < 4; ++ct) {
        const int n0 = csplit * 512 + ct * 128;
        const unsigned short* Bp = etb + (size_t)n0 * 512;
        frag_cd acc[4][4] = {};
        __syncthreads();  // drains prologue/tail stage of this ct
#pragma unroll 1
        for (int p = 0; p < 3; ++p) {
            stage_async(Ap, 512, (2 * p + 1) * 64, sA1, t);
            stage_async(Bp, 512, (2 * p + 1) * 64, sB1, t);
            __builtin_amdgcn_s_setprio(1);
            mfma_tile_swp(sA0, sB0, lane, wr, wc, acc);
            __builtin_amdgcn_s_setprio(0);
            __syncthreads();
            stage_async(Ap, 512, (2 * p + 2) * 64, sA0, t);
            stage_async(Bp, 512, (2 * p + 2) * 64, sB0, t);
            __builtin_amdgcn_s_setprio(1);
            mfma_tile_swp(sA1, sB1, lane, wr, wc, acc);
            __builtin_amdgcn_s_setprio(0);
            __syncthreads();
        }
        stage_async(Ap, 512, 7 * 64, sA1, t);
        stage_async(Bp, 512, 7 * 64, sB1, t);
        __builtin_amdgcn_s_setprio(1);
        mfma_tile_swp(sA0, sB0, lane, wr, wc, acc);
        __builtin_amdgcn_s_setprio(0);
        __syncthreads();
        if (ct < 3) {  // tail: stage next ct's k=0 into sA0/sB0 (disjoint from sA1/sB1)
            stage_async(Ap, 512, 0, sA0, t);
            stage_async(etb + (size_t)(n0 + 128) * 512, 512, 0, sB0, t);
        }
        __builtin_amdgcn_s_setprio(1);
        mfma_tile_swp(sA1, sB1, lane, wr, wc, acc);
        __builtin_amdgcn_s_setprio(0);
        // in-register scan of this ct's S^T tile (overlaps the tail stage's latency)
        const int base_ck = 8191 - (n0 + wc * 64 + ((lane >> 4) << 2));
#pragma unroll
        for (int i = 0; i < 4; ++i)
#pragma unroll
            for (int j = 0; j < 4; ++j)
#pragma unroll
                for (int r = 0; r < 4; ++r) {
                    unsigned key = (mono(acc[i][j][r]) & 0xFFFFE000u) |
                                   (unsigned)(base_ck - j * 16 - r);
                    kins(kl[i], key);
                }
    }
    // merge across lane>>4 groups (same eh row, disjoint et cols): xor 16 then 32
#pragma unroll
    for (int i = 0; i < 4; ++i) {
#pragma unroll
        for (int j = 0; j < 6; ++j) {
            unsigned ok = (unsigned)__shfl_xor((int)kl[i][j], 16, 64);
            kins(kl[i], ok);
        }
#pragma unroll
        for (int j = 0; j < 6; ++j) {
            unsigned ok = (unsigned)__shfl_xor((int)kl[i][j], 32, 64);
            kins(kl[i], ok);
        }
    }
    // cross-wave (wc) merge via small LDS buffer
    __syncthreads();  // all GEMM reads done; smem reusable
    if (wc == 1 && (lane >> 4) == 0) {
#pragma unroll
        for (int i = 0; i < 4; ++i) {
            int row = wr * 64 + i * 16 + lane;
#pragma unroll
            for (int j = 0; j < 6; ++j) xbuf[row * 6 + j] = kl[i][j];
        }
    }
    __syncthreads();
    if (wc == 0 && (lane >> 4) == 0) {
#pragma unroll
        for (int i = 0; i < 4; ++i) {
            int row = wr * 64 + i * 16 + lane;
#pragma unroll
            for (int j = 0; j < 6; ++j) kins(kl[i], xbuf[row * 6 + j]);
            size_t o = ((size_t)(m0 + row) * 16 + csplit) * 6;
#pragma unroll
            for (int j = 0; j < 6; ++j) pk[o + j] = kl[i][j];
        }
    }
}

// ---- merge 16 partial top-6 key lists -> final top-6 per row; decode ----
__global__ void k_merge_topk(const unsigned* __restrict__ pk,
                             float* __restrict__ tw, int* __restrict__ ti) {
    int r = blockIdx.x * 256 + threadIdx.x;
    if (r >= 8192) return;
    unsigned v[6] = {0, 0, 0, 0, 0, 0};
    for (int s2 = 0; s2 < 16; ++s2) {
        const unsigned* p = pk + ((size_t)r * 16 + s2) * 6;
#pragma unroll
        for (int j = 0; j < 6; ++j) kins(v, p[j]);
    }
#pragma unroll
    for (int j = 0; j < 6; ++j) {
        tw[r * 6 + j] = unmono(v[j] & 0xFFFFE000u) * SCALE_C;
        ti[r * 6 + j] = 8191 - (int)(v[j] & 8191u);
    }
}

// ---- fast tanh: 1 - 2/(e^{2x}+1); exact at +/-inf, ~1e-6 abs err ----
DEV float ftanh(float x) {
    float t = __expf(2.f * x);
    return 1.f - 2.f * __builtin_amdgcn_rcpf(t + 1.f);
}

// ---- per-node neighbor aggregation: one wave per node ----
__global__ __launch_bounds__(256) void k_agg(
    const unsigned short* __restrict__ ehb, const unsigned short* __restrict__ etb,
    const float* __restrict__ tw, const int* __restrict__ ti,
    unsigned short* __restrict__ sb, unsigned short* __restrict__ pb) {
    const int t = threadIdx.x, lane = t & 63, wid = t >> 6;
    const int node = blockIdx.x * 4 + wid;
    const int d0 = lane * 8;
    float w[6]; int idx[6];
#pragma unroll
    for (int k = 0; k < 6; ++k) { w[k] = tw[node * 6 + k]; idx[k] = ti[node * 6 + k]; }
    float mx = w[0];
#pragma unroll
    for (int k = 1; k < 6; ++k) mx = fmaxf(mx, w[k]);
    float pr[6], s = 0.f;
#pragma unroll
    for (int k = 0; k < 6; ++k) { pr[k] = __expf(w[k] - mx); s += pr[k]; }
    float inv = 1.f / s;
#pragma unroll
    for (int k = 0; k < 6; ++k) pr[k] *= inv;

    float eh[8]; unpack8(*(const uint4*)(ehb + (size_t)node * 512 + d0), eh);
    float nb[6][8];
#pragma unroll
    for (int k = 0; k < 6; ++k) unpack8(*(const uint4*)(etb + (size_t)idx[k] * 512 + d0), nb[k]);

    float kw[6] = {};
#pragma unroll
    for (int k = 0; k < 6; ++k) {
        float pk2 = pr[k];
#pragma unroll
        for (int j = 0; j < 8; ++j) {
            float ehr = pk2 * nb[k][j] + (1.f - pk2) * eh[j];
            float g = ftanh(eh[j] + ehr);
            kw[k] += nb[k][j] * g;
        }
    }
#pragma unroll
    for (int k = 0; k < 6; ++k)
#pragma unroll
        for (int o = 1; o < 64; o <<= 1) kw[k] += __shfl_xor(kw[k], o, 64);
    float m2 = kw[0];
#pragma unroll
    for (int k = 1; k < 6; ++k) m2 = fmaxf(m2, kw[k]);
    float kp[6], s2 = 0.f;
#pragma unroll
    for (int k = 0; k < 6; ++k) { kp[k] = __expf(kw[k] - m2); s2 += kp[k]; }
    float inv2 = 1.f / s2;
#pragma unroll
    for (int k = 0; k < 6; ++k) kp[k] *= inv2;

    float sv[8], pv[8];
#pragma unroll
    for (int j = 0; j < 8; ++j) {
        float en = 0.f;
#pragma unroll
        for (int k = 0; k < 6; ++k) en += kp[k] * nb[k][j];
        sv[j] = eh[j] + en;
        pv[j] = eh[j] * en;
    }
    *(uint4*)(sb + (size_t)node * 512 + d0) = pack8(sv);
    *(uint4*)(pb + (size_t)node * 512 + d0) = pack8(pv);
}

// ---- final: node-mean -> LN -> classifier ----
DEV float blocksum512(float v, float* red, int lane, int wid) {
#pragma unroll
    for (int o = 1; o < 64; o <<= 1) v += __shfl_xor(v, o, 64);
    __syncthreads();
    if (lane == 0) red[wid] = v;
    __syncthreads();
    float s = 0.f;
#pragma unroll
    for (int w2 = 0; w2 < 8; ++w2) s += red[w2];
    return s;
}

__global__ __launch_bounds__(512) void k_final(
    const float* __restrict__ colsum_emb, const float* __restrict__ ln_g,
    const float* __restrict__ ln_b, const float* __restrict__ cls_w,
    const float* __restrict__ cls_b, float* __restrict__ out) {
    __shared__ float red[8];
    const int t = threadIdx.x, lane = t & 63, wid = t >> 6;
    float h = colsum_emb[t] * (1.f / 8192.f);
    float mu = blocksum512(h, red, lane, wid) * (1.f / 512.f);
    float d = h - mu;
    float var = blocksum512(d * d, red, lane, wid) * (1.f / 512.f);
    float y = d * rsqrtf(var + 1e-5f) * ln_g[t] + ln_b[t];
    float s0 = blocksum512(y * cls_w[t * 2 + 0], red, lane, wid);
    float s1 = blocksum512(y * cls_w[t * 2 + 1], red, lane, wid);
    if (t == 0) { out[0] = s0 + cls_b[0]; out[1] = s1 + cls_b[1]; }
}

extern "C" void kernel_launch(void* const* d_in, const int* in_sizes, int n_in,
                              void* d_out, int out_size, void* d_ws, size_t ws_size,
                              hipStream_t stream) {
    (void)in_sizes; (void)n_in; (void)out_size; (void)ws_size;
    const float* feats = (const float*)d_in[0];
    const float* fc1_w = (const float*)d_in[1];
    const float* fc1_b = (const float*)d_in[2];
    const float* wh_w  = (const float*)d_in[3];
    const float* wh_b  = (const float*)d_in[4];
    const float* wt_w  = (const float*)d_in[5];
    const float* wt_b  = (const float*)d_in[6];
    const float* l1_w  = (const float*)d_in[7];
    const float* l1_b  = (const float*)d_in[8];
    const float* l2_w  = (const float*)d_in[9];
    const float* l2_b  = (const float*)d_in[10];
    const float* ln_g  = (const float*)d_in[11];
    const float* ln_b  = (const float*)d_in[12];
    const float* cls_w = (const float*)d_in[13];
    const float* cls_b = (const float*)d_in[14];

    char* ws = (char*)d_ws;
    size_t off = 0;
    auto alloc = [&](size_t bytes) {
        char* p = ws + off;
        off += (bytes + 255) & ~(size_t)255;
        return p;
    };
    unsigned short* fb   = (unsigned short*)alloc(8192ull * 384 * 2);
    unsigned short* xb   = (unsigned short*)alloc(8192ull * 512 * 2);
    unsigned short* ehb  = (unsigned short*)alloc(8192ull * 512 * 2);
    unsigned short* etb  = (unsigned short*)alloc(8192ull * 512 * 2);
    unsigned short* sb   = (unsigned short*)alloc(8192ull * 512 * 2);
    unsigned short* pb   = (unsigned short*)alloc(8192ull * 512 * 2);
    unsigned short* wfc1T = (unsigned short*)alloc(512ull * 384 * 2);
    unsigned short* whT  = (unsigned short*)alloc(512ull * 512 * 2);
    unsigned short* wtT  = (unsigned short*)alloc(512ull * 512 * 2);
    unsigned short* l1T  = (unsigned short*)alloc(512ull * 512 * 2);
    unsigned short* l2T  = (unsigned short*)alloc(512ull * 512 * 2);
    float* colsum     = (float*)alloc(512 * 4);
    float* colsum_emb = (float*)alloc(512 * 4);
    float* cvh = (float*)alloc(512 * 4);
    float* cvt = (float*)alloc(512 * 4);
    unsigned* pk = (unsigned*)alloc(8192ull * 16 * 6 * 4);
    float* tw = (float*)alloc(8192ull * 6 * 4);
    int*   ti = (int*)alloc(8192ull * 6 * 4);

    hipMemsetAsync(colsum, 0, 512 * 4, stream);
    hipMemsetAsync(colsum_emb, 0, 512 * 4, stream);

    // fused conv + 5 LDS-tiled weight transposes (wh/wt scaled 0.5)
    k_prep<<<dim3(256, 1, 6), 256, 0, stream>>>(
        feats, fc1_w, wh_w, wt_w, l1_w, l2_w, fb, wfc1T, whT, wtT, l1T, l2T);

    // x0 = lrelu(feats@fc1 + b), colsum(x0)  [xb holds x0; mean folded into bias below]
    k_gemm<1, 1><<<dim3(64, 4, 1), 256, 0, stream>>>(
        fb, fb, wfc1T, wfc1T, fc1_b, fc1_b, xb, xb, colsum, 8192, 512, 384);
    // rank-1 fold: cv = b + (1/8192)*colsum@(0.5W) via L2-hot bf16 whT/wtT
    k_rank1<<<dim3(64, 2), 512, 0, stream>>>(colsum, whT, wtT, wh_b, wt_b, cvh, cvt);
    // e_h and e_t in one dual launch: e = x0 @ (0.5W) + cv
    k_gemm<0, 0><<<dim3(64, 4, 2), 256, 0, stream>>>(
        xb, xb, whT, wtT, cvh, cvt, ehb, etb, nullptr, 8192, 512, 512);
    // attn logits + fused in-register top-6 (128x128 tiles, 16 col-splits), then merge+decode
    k_attn_topk<<<dim3(64, 16), 256, 0, stream>>>(ehb, etb, pk);
    k_merge_topk<<<32, 256, 0, stream>>>(pk, tw, ti);
    // neighbor aggregation -> s = e_h + e_Nh, p = e_h * e_Nh (bf16)
    k_agg<<<2048, 256, 0, stream>>>(ehb, etb, tw, ti, sb, pb);
    // emb colsums in one dual launch (never materialize emb)
    k_gemm<1, 2><<<dim3(64, 4, 2), 256, 0, stream>>>(
        sb, pb, l1T, l2T, l1_b, l2_b, nullptr, nullptr, colsum_emb, 8192, 512, 512);
    // mean -> LN -> classifier
    k_final<<<1, 512, 0, stream>>>(colsum_emb, ln_g, ln_b, cls_w, cls_b, (float*)d_out);
}

// Round 12
// 160.600 us; speedup vs baseline: 1.1911x; 1.0495x over previous
//
#include <hip/hip_runtime.h>
#include <math.h>

#define DEV __device__ __forceinline__

// ---- MFMA fragment types (gfx950 16x16x32 bf16) ----
using frag_ab = __attribute__((ext_vector_type(8))) short;  // 8 bf16 (4 VGPRs)
using frag_cd = __attribute__((ext_vector_type(4))) float;  // 4 fp32

static constexpr float SCALE_C = 0.04419417382415922f;  // 512^-0.5

// ---- bf16 helpers (RNE) ----
DEV unsigned short f2bf(float f) {
    unsigned u = __float_as_uint(f);
    unsigned r = (u + 0x7FFFu + ((u >> 16) & 1u)) >> 16;
    return (unsigned short)r;
}
DEV float bf2f(unsigned short h) { return __uint_as_float(((unsigned)h) << 16); }

DEV void unpack8(uint4 q, float f[8]) {
    f[0] = bf2f((unsigned short)(q.x & 0xFFFFu)); f[1] = bf2f((unsigned short)(q.x >> 16));
    f[2] = bf2f((unsigned short)(q.y & 0xFFFFu)); f[3] = bf2f((unsigned short)(q.y >> 16));
    f[4] = bf2f((unsigned short)(q.z & 0xFFFFu)); f[5] = bf2f((unsigned short)(q.z >> 16));
    f[6] = bf2f((unsigned short)(q.w & 0xFFFFu)); f[7] = bf2f((unsigned short)(q.w >> 16));
}
DEV uint4 pack8(const float f[8]) {
    uint4 q;
    q.x = (unsigned)f2bf(f[0]) | ((unsigned)f2bf(f[1]) << 16);
    q.y = (unsigned)f2bf(f[2]) | ((unsigned)f2bf(f[3]) << 16);
    q.z = (unsigned)f2bf(f[4]) | ((unsigned)f2bf(f[5]) << 16);
    q.w = (unsigned)f2bf(f[6]) | ((unsigned)f2bf(f[7]) << 16);
    return q;
}

// ---- order-preserving float<->u32 (monotone key) ----
DEV unsigned mono(float f) {
    unsigned u = __float_as_uint(f);
    return u ^ ((unsigned)((int)u >> 31) | 0x80000000u);
}
DEV float unmono(unsigned k) {
    unsigned u = (k & 0x80000000u) ? (k & 0x7FFFFFFFu) : ~k;
    return __uint_as_float(u);
}

// ---- async global->LDS 16B (direct-to-LDS DMA; dest = wave base + lane*16) ----
DEV void gload_lds16(const void* g, void* l) {
    __builtin_amdgcn_global_load_lds(
        (const __attribute__((address_space(1))) void*)g,
        (__attribute__((address_space(3))) void*)l, 16, 0, 0);
}

// ---- fused prep: z=0..4 LDS-tiled weight transposes ([K][512]f32 -> [512][K]bf16,
// wh/wt scaled by 0.5 for the rank-1 mean fold), z=5 feats conv ----
__global__ void k_prep(const float* __restrict__ feats, const float* __restrict__ fc1_w,
                       const float* __restrict__ wh_w, const float* __restrict__ wt_w,
                       const float* __restrict__ l1_w, const float* __restrict__ l2_w,
                       unsigned short* __restrict__ fb, unsigned short* __restrict__ wfc1T,
                       unsigned short* __restrict__ whT, unsigned short* __restrict__ wtT,
                       unsigned short* __restrict__ l1T, unsigned short* __restrict__ l2T) {
    const int z = blockIdx.z;
    const int tid = threadIdx.x;
    if (z == 5) {  // conv feats f32 -> bf16, grid-stride
        for (int i = (blockIdx.x * 256 + tid) * 4; i < 8192 * 384; i += 256 * 256 * 4) {
            float4 v = *(const float4*)(feats + i);
            ushort4 o;
            o.x = f2bf(v.x); o.y = f2bf(v.y); o.z = f2bf(v.z); o.w = f2bf(v.w);
            *(ushort4*)(fb + i) = o;
        }
        return;
    }
    const float* s = z == 0 ? fc1_w : z == 1 ? wh_w : z == 2 ? wt_w : z == 3 ? l1_w : l2_w;
    unsigned short* d = z == 0 ? wfc1T : z == 1 ? whT : z == 2 ? wtT : z == 3 ? l1T : l2T;
    const int K = z == 0 ? 384 : 512;
    const float scale = (z == 1 || z == 2) ? 0.5f : 1.0f;
    const int ntk = K >> 6;
    const int t = blockIdx.x;
    if (t >= ntk * 8) return;
    const int k0 = (t % ntk) * 64, n0 = (t / ntk) * 64;
    __shared__ short tile[64 * 68];  // [n][k], stride 68
    // phase 1: coalesced f32 read, transposed bf16 scatter into LDS
#pragma unroll
    for (int p = 0; p < 4; ++p) {
        int kk = p * 16 + (tid >> 4);
        int nn = (tid & 15) * 4;
        float4 v = *(const float4*)(s + (size_t)(k0 + kk) * 512 + n0 + nn);
        tile[(nn + 0) * 68 + kk] = (short)f2bf(v.x * scale);
        tile[(nn + 1) * 68 + kk] = (short)f2bf(v.y * scale);
        tile[(nn + 2) * 68 + kk] = (short)f2bf(v.z * scale);
        tile[(nn + 3) * 68 + kk] = (short)f2bf(v.w * scale);
    }
    __syncthreads();
    // phase 2: row reads from LDS, coalesced 16B global stores
#pragma unroll
    for (int p = 0; p < 2; ++p) {
        int rr = p * 32 + (tid >> 3);
        int cc = (tid & 7) * 8;
        const short* rp = &tile[rr * 68 + cc];
        uint2 a = *(const uint2*)(rp);
        uint2 b = *(const uint2*)(rp + 4);
        uint4 o = {a.x, a.y, b.x, b.y};
        *(uint4*)(d + (size_t)(n0 + rr) * K + k0 + cc) = o;
    }
}

// ---- rank-1 mean fold: cv[n] = b[n] + (1/8192) * <colsum, whT_row_n>
// (whT holds 0.5*W in bf16, L2-hot; one wave per output n, coalesced 1KB row read) ----
__global__ __launch_bounds__(512) void k_rank1(
    const float* __restrict__ colsum,
    const unsigned short* __restrict__ whT, const unsigned short* __restrict__ wtT,
    const float* __restrict__ wh_b, const float* __restrict__ wt_b,
    float* __restrict__ cvh, float* __restrict__ cvt) {
    const int lane = threadIdx.x & 63, wid = threadIdx.x >> 6;
    const int n = blockIdx.x * 8 + wid;  // 64 blocks x 8 waves = 512 outputs
    const unsigned short* W = blockIdx.y ? wtT : whT;
    const float* b = blockIdx.y ? wt_b : wh_b;
    float* cv = blockIdx.y ? cvt : cvh;
    float f[8];
    unpack8(*(const uint4*)(W + (size_t)n * 512 + lane * 8), f);
    float4 c0 = *(const float4*)(colsum + lane * 8);
    float4 c1 = *(const float4*)(colsum + lane * 8 + 4);
    float s = f[0] * c0.x + f[1] * c0.y + f[2] * c0.z + f[3] * c0.w +
              f[4] * c1.x + f[5] * c1.y + f[6] * c1.z + f[7] * c1.w;
#pragma unroll
    for (int o = 1; o < 64; o <<= 1) s += __shfl_xor(s, o, 64);
    if (lane == 0) cv[n] = b[n] + s * (1.f / 8192.f);
}

// ---- staging: 128 rows x 64 bf16 (16KB), XOR-swizzled source, linear LDS dest ----
DEV void stage_async(const unsigned short* __restrict__ g, int ld, int k0, char* lds, int t) {
    const int sub = t >> 3;
    const int b = (t & 7) << 4;
    const int bs = b ^ ((sub & 7) << 4);
    const char* gb = (const char*)(g + k0) + (size_t)sub * (size_t)(ld * 2) + bs;
    char* lb = lds + ((t >> 6) << 10);
    const size_t rstep = (size_t)32 * (ld * 2);
#pragma unroll
    for (int r = 0; r < 4; ++r)
        gload_lds16(gb + r * rstep, lb + r * 4096);
}

// ---- one 128x128x64 MFMA step (normal orientation: D row <- A-op(As)) ----
DEV void mfma_tile(const char* As, const char* Bs, int lane, int wr, int wc, frag_cd (&acc)[4][4]) {
#pragma unroll
    for (int ks = 0; ks < 2; ++ks) {
        const int boff = ks * 64 + ((lane >> 4) << 4);
        frag_ab av[4];
#pragma unroll
        for (int f = 0; f < 4; ++f) {
            int ra = wr * 64 + f * 16 + (lane & 15);
            av[f] = *(const frag_ab*)(As + ra * 128 + (boff ^ ((ra & 7) << 4)));
        }
#pragma unroll
        for (int j = 0; j < 4; ++j) {
            int rb = wc * 64 + j * 16 + (lane & 15);
            frag_ab bv = *(const frag_ab*)(Bs + rb * 128 + (boff ^ ((rb & 7) << 4)));
#pragma unroll
            for (int i = 0; i < 4; ++i)
                acc[i][j] = __builtin_amdgcn_mfma_f32_16x16x32_bf16(av[i], bv, acc[i][j], 0, 0, 0);
        }
    }
}

// ---- swapped-operand variant: acc[i][j] = mfma(et_frag(j), eh_frag(i)) = S^T tile.
// Lane holds, per i: eh row = wr*64+i*16+(lane&15); et cols j*16+(lane>>4)*4+r.
DEV void mfma_tile_swp(const char* As, const char* Bs, int lane, int wr, int wc, frag_cd (&acc)[4][4]) {
#pragma unroll
    for (int ks = 0; ks < 2; ++ks) {
        const int boff = ks * 64 + ((lane >> 4) << 4);
        frag_ab av[4];
#pragma unroll
        for (int f = 0; f < 4; ++f) {
            int ra = wr * 64 + f * 16 + (lane & 15);
            av[f] = *(const frag_ab*)(As + ra * 128 + (boff ^ ((ra & 7) << 4)));
        }
#pragma unroll
        for (int j = 0; j < 4; ++j) {
            int rb = wc * 64 + j * 16 + (lane & 15);
            frag_ab bv = *(const frag_ab*)(Bs + rb * 128 + (boff ^ ((rb & 7) << 4)));
#pragma unroll
            for (int i = 0; i < 4; ++i)
                acc[i][j] = __builtin_amdgcn_mfma_f32_16x16x32_bf16(bv, av[i], acc[i][j], 0, 0, 0);
        }
    }
}

// ---- generic bf16 GEMM, 2-stage software pipeline (static buffers, unroll 1);
// blockIdx.z selects job. C = act(A @ BT^T + bias); EPI: 0=store, 1=store+colsum, 2=colsum only ----
template <int ACT, int EPI>
__global__ __launch_bounds__(256, 2) void k_gemm(
    const unsigned short* __restrict__ A0, const unsigned short* __restrict__ A1,
    const unsigned short* __restrict__ B0, const unsigned short* __restrict__ B1,
    const float* __restrict__ bias0, const float* __restrict__ bias1,
    unsigned short* __restrict__ out0, unsigned short* __restrict__ out1,
    float* __restrict__ colsum, int M, int N, int K) {
    __shared__ __align__(16) char smem[65536];
    __shared__ float colacc[128];
    char* sA0 = smem;
    char* sA1 = smem + 16384;
    char* sB0 = smem + 32768;
    char* sB1 = smem + 49152;
    const int z = blockIdx.z;
    const unsigned short* A = z ? A1 : A0;
    const unsigned short* BT = z ? B1 : B0;
    const float* bias = z ? bias1 : bias0;
    unsigned short* out = z ? out1 : out0;
    const int t = threadIdx.x;
    const int lane = t & 63, wid = t >> 6, wr = wid >> 1, wc = wid & 1;
    const int m0 = blockIdx.x * 128, n0 = blockIdx.y * 128;
    if (EPI >= 1 && t < 128) colacc[t] = 0.f;
    const unsigned short* Ap = A + (size_t)m0 * K;
    const unsigned short* Bp = BT + (size_t)n0 * K;
    frag_cd acc[4][4] = {};
    const int nt = K >> 6;  // even, >= 4
    stage_async(Ap, K, 0, sA0, t);
    stage_async(Bp, K, 0, sB0, t);
    __syncthreads();
#pragma unroll 1
    for (int tt = 0; tt < nt - 2; tt += 2) {
        stage_async(Ap, K, (tt + 1) * 64, sA1, t);
        stage_async(Bp, K, (tt + 1) * 64, sB1, t);
        mfma_tile(sA0, sB0, lane, wr, wc, acc);
        __syncthreads();
        stage_async(Ap, K, (tt + 2) * 64, sA0, t);
        stage_async(Bp, K, (tt + 2) * 64, sB0, t);
        mfma_tile(sA1, sB1, lane, wr, wc, acc);
        __syncthreads();
    }
    stage_async(Ap, K, (nt - 1) * 64, sA1, t);
    stage_async(Bp, K, (nt - 1) * 64, sB1, t);
    mfma_tile(sA0, sB0, lane, wr, wc, acc);
    __syncthreads();
    mfma_tile(sA1, sB1, lane, wr, wc, acc);
    // epilogue
    float bval[4];
#pragma unroll
    for (int j = 0; j < 4; ++j) bval[j] = bias[n0 + wc * 64 + j * 16 + (lane & 15)];
#pragma unroll
    for (int i = 0; i < 4; ++i) {
#pragma unroll
        for (int j = 0; j < 4; ++j) {
            float cs = 0.f;
#pragma unroll
            for (int r = 0; r < 4; ++r) {
                float v = acc[i][j][r] + bval[j];
                if (ACT) v = v > 0.f ? v : 0.01f * v;
                if (EPI != 2) {
                    int row = m0 + wr * 64 + i * 16 + (lane >> 4) * 4 + r;
                    int col = n0 + wc * 64 + j * 16 + (lane & 15);
                    out[(size_t)row * N + col] = f2bf(v);
                }
                cs += v;
            }
            if (EPI >= 1) atomicAdd(&colacc[wc * 64 + j * 16 + (lane & 15)], cs);
        }
    }
    if (EPI >= 1) {
        __syncthreads();
        if (t < 128) atomicAdd(&colsum[n0 + t], colacc[t]);
    }
}

// ---- sorted-desc top-6 key insert via med3 (6 ops, dep depth 1):
// v[0]'=max(v0,k); v[j]'=med3(v[j-1]_old, v[j], k) ----
DEV unsigned med3u(unsigned a, unsigned b, unsigned c) {
    unsigned r;
    asm("v_med3_u32 %0, %1, %2, %3" : "=v"(r) : "v"(a), "v"(b), "v"(c));
    return r;
}
DEV void kins(unsigned (&v)[6], unsigned k) {
    unsigned t0 = v[0], t1 = v[1], t2 = v[2], t3 = v[3], t4 = v[4];
    v[0] = v[0] > k ? v[0] : k;
    v[1] = med3u(t0, v[1], k);
    v[2] = med3u(t1, v[2], k);
    v[3] = med3u(t2, v[3], k);
    v[4] = med3u(t3, v[4], k);
    v[5] = med3u(t4, v[5], k);
}

// ---- fused attn-logit GEMM + fully in-register top-6 (swapped-operand S^T) ----
// grid (64 row-blocks, 8 col-splits); block = 128 rows x 1024 cols, 256 thr.
__global__ __launch_bounds__(256, 2) void k_attn_topk(
    const unsigned short* __restrict__ ehb, const unsigned short* __restrict__ etb,
    unsigned* __restrict__ pk) {
    __shared__ __align__(16) char smem[65536];
    char* sA0 = smem;
    char* sA1 = smem + 16384;
    char* sB0 = smem + 32768;
    char* sB1 = smem + 49152;
    unsigned* xbuf = (unsigned*)smem;  // [128][6] cross-wave merge buf (3KB), used once at end
    const int t = threadIdx.x;
    const int lane = t & 63, wid = t >> 6, wr = wid >> 1, wc = wid & 1;
    const int m0 = blockIdx.x * 128;
    const int csplit = blockIdx.y;
    const unsigned short* Ap = ehb + (size_t)m0 * 512;
    unsigned kl[4][6] = {};  // per-row top-6 key lists (key 0 < any real key)

    // prologue: stage ct=0, k=0
    stage_async(Ap, 512, 0, sA0, t);
    stage_async(etb + (size_t)(csplit * 1024) * 512, 512, 0, sB0, t);

#pragma unroll 1
    for (int ct = 0; ct < 8; ++ct) {
        const int n0 = csplit * 1024 + ct * 128;
        const unsigned short* Bp = etb + (size_t)n0 * 512;
        frag_cd acc[4][4] = {};
        __syncthreads();  // drains prologue/tail stage of this ct
#pragma unroll 1
        for (int p = 0; p < 3; ++p) {
            stage_async(Ap, 512, (2 * p + 1) * 64, sA1, t);
            stage_async(Bp, 512, (2 * p + 1) * 64, sB1, t);
            __builtin_amdgcn_s_setprio(1);
            mfma_tile_swp(sA0, sB0, lane, wr, wc, acc);
            __builtin_amdgcn_s_setprio(0);
            __syncthreads();
            stage_async(Ap, 512, (2 * p + 2) * 64, sA0, t);
            stage_async(Bp, 512, (2 * p + 2) * 64, sB0, t);
            __builtin_amdgcn_s_setprio(1);
            mfma_tile_swp(sA1, sB1, lane, wr, wc, acc);
            __builtin_amdgcn_s_setprio(0);
            __syncthreads();
        }
        stage_async(Ap, 512, 7 * 64, sA1, t);
        stage_async(Bp, 512, 7 * 64, sB1, t);
        __builtin_amdgcn_s_setprio(1);
        mfma_tile_swp(sA0, sB0, lane, wr, wc, acc);
        __builtin_amdgcn_s_setprio(0);
        __syncthreads();
        if (ct < 7) {  // tail: stage next ct's k=0 into sA0/sB0 (disjoint from sA1/sB1)
            stage_async(Ap, 512, 0, sA0, t);
            stage_async(etb + (size_t)(n0 + 128) * 512, 512, 0, sB0, t);
        }
        __builtin_amdgcn_s_setprio(1);
        mfma_tile_swp(sA1, sB1, lane, wr, wc, acc);
        __builtin_amdgcn_s_setprio(0);
        // in-register scan of this ct's S^T tile (overlaps the tail stage's latency)
        const int base_ck = 8191 - (n0 + wc * 64 + ((lane >> 4) << 2));
#pragma unroll
        for (int i = 0; i < 4; ++i)
#pragma unroll
            for (int j = 0; j < 4; ++j)
#pragma unroll
                for (int r = 0; r < 4; ++r) {
                    unsigned key = (mono(acc[i][j][r]) & 0xFFFFE000u) |
                                   (unsigned)(base_ck - j * 16 - r);
                    kins(kl[i], key);
                }
    }
    // merge across lane>>4 groups (same eh row, disjoint et cols): xor 16 then 32
#pragma unroll
    for (int i = 0; i < 4; ++i) {
#pragma unroll
        for (int j = 0; j < 6; ++j) {
            unsigned ok = (unsigned)__shfl_xor((int)kl[i][j], 16, 64);
            kins(kl[i], ok);
        }
#pragma unroll
        for (int j = 0; j < 6; ++j) {
            unsigned ok = (unsigned)__shfl_xor((int)kl[i][j], 32, 64);
            kins(kl[i], ok);
        }
    }
    // cross-wave (wc) merge via small LDS buffer
    __syncthreads();  // all GEMM reads done; smem reusable
    if (wc == 1 && (lane >> 4) == 0) {
#pragma unroll
        for (int i = 0; i < 4; ++i) {
            int row = wr * 64 + i * 16 + lane;
#pragma unroll
            for (int j = 0; j < 6; ++j) xbuf[row * 6 + j] = kl[i][j];
        }
    }
    __syncthreads();
    if (wc == 0 && (lane >> 4) == 0) {
#pragma unroll
        for (int i = 0; i < 4; ++i) {
            int row = wr * 64 + i * 16 + lane;
#pragma unroll
            for (int j = 0; j < 6; ++j) kins(kl[i], xbuf[row * 6 + j]);
            size_t o = ((size_t)(m0 + row) * 8 + csplit) * 6;
#pragma unroll
            for (int j = 0; j < 6; ++j) pk[o + j] = kl[i][j];
        }
    }
}

// ---- fast tanh: 1 - 2/(e^{2x}+1); exact at +/-inf, ~1e-6 abs err ----
DEV float ftanh(float x) {
    float t = __expf(2.f * x);
    return 1.f - 2.f * __builtin_amdgcn_rcpf(t + 1.f);
}

// ---- per-node neighbor aggregation: one wave per node.
// Fuses the 8x6 partial top-6 key merge (redundant across lanes; broadcast loads). ----
__global__ __launch_bounds__(256) void k_agg(
    const unsigned short* __restrict__ ehb, const unsigned short* __restrict__ etb,
    const unsigned* __restrict__ pk,
    unsigned short* __restrict__ sb, unsigned short* __restrict__ pb) {
    const int t = threadIdx.x, lane = t & 63, wid = t >> 6;
    const int node = blockIdx.x * 4 + wid;
    const int d0 = lane * 8;
    // merge 48 partial keys -> top-6 (all lanes redundantly; same-address = broadcast)
    const unsigned* p = pk + (size_t)node * 48;
    unsigned v[6] = {0, 0, 0, 0, 0, 0};
#pragma unroll
    for (int s2 = 0; s2 < 48; ++s2) kins(v, p[s2]);
    float w[6]; int idx[6];
#pragma unroll
    for (int k = 0; k < 6; ++k) {
        w[k] = unmono(v[k] & 0xFFFFE000u) * SCALE_C;
        idx[k] = 8191 - (int)(v[k] & 8191u);
    }
    float mx = w[0];
#pragma unroll
    for (int k = 1; k < 6; ++k) mx = fmaxf(mx, w[k]);
    float pr[6], s = 0.f;
#pragma unroll
    for (int k = 0; k < 6; ++k) { pr[k] = __expf(w[k] - mx); s += pr[k]; }
    float inv = 1.f / s;
#pragma unroll
    for (int k = 0; k < 6; ++k) pr[k] *= inv;

    float eh[8]; unpack8(*(const uint4*)(ehb + (size_t)node * 512 + d0), eh);
    float nb[6][8];
#pragma unroll
    for (int k = 0; k < 6; ++k) unpack8(*(const uint4*)(etb + (size_t)idx[k] * 512 + d0), nb[k]);

    float kw[6] = {};
#pragma unroll
    for (int k = 0; k < 6; ++k) {
        float pk2 = pr[k];
#pragma unroll
        for (int j = 0; j < 8; ++j) {
            float ehr = pk2 * nb[k][j] + (1.f - pk2) * eh[j];
            float g = ftanh(eh[j] + ehr);
            kw[k] += nb[k][j] * g;
        }
    }
#pragma unroll
    for (int k = 0; k < 6; ++k)
#pragma unroll
        for (int o = 1; o < 64; o <<= 1) kw[k] += __shfl_xor(kw[k], o, 64);
    float m2 = kw[0];
#pragma unroll
    for (int k = 1; k < 6; ++k) m2 = fmaxf(m2, kw[k]);
    float kp[6], s2 = 0.f;
#pragma unroll
    for (int k = 0; k < 6; ++k) { kp[k] = __expf(kw[k] - m2); s2 += kp[k]; }
    float inv2 = 1.f / s2;
#pragma unroll
    for (int k = 0; k < 6; ++k) kp[k] *= inv2;

    float sv[8], pv[8];
#pragma unroll
    for (int j = 0; j < 8; ++j) {
        float en = 0.f;
#pragma unroll
        for (int k = 0; k < 6; ++k) en += kp[k] * nb[k][j];
        sv[j] = eh[j] + en;
        pv[j] = eh[j] * en;
    }
    *(uint4*)(sb + (size_t)node * 512 + d0) = pack8(sv);
    *(uint4*)(pb + (size_t)node * 512 + d0) = pack8(pv);
}

// ---- final: node-mean -> LN -> classifier ----
DEV float blocksum512(float v, float* red, int lane, int wid) {
#pragma unroll
    for (int o = 1; o < 64; o <<= 1) v += __shfl_xor(v, o, 64);
    __syncthreads();
    if (lane == 0) red[wid] = v;
    __syncthreads();
    float s = 0.f;
#pragma unroll
    for (int w2 = 0; w2 < 8; ++w2) s += red[w2];
    return s;
}

__global__ __launch_bounds__(512) void k_final(
    const float* __restrict__ colsum_emb, const float* __restrict__ ln_g,
    const float* __restrict__ ln_b, const float* __restrict__ cls_w,
    const float* __restrict__ cls_b, float* __restrict__ out) {
    __shared__ float red[8];
    const int t = threadIdx.x, lane = t & 63, wid = t >> 6;
    float h = colsum_emb[t] * (1.f / 8192.f);
    float mu = blocksum512(h, red, lane, wid) * (1.f / 512.f);
    float d = h - mu;
    float var = blocksum512(d * d, red, lane, wid) * (1.f / 512.f);
    float y = d * rsqrtf(var + 1e-5f) * ln_g[t] + ln_b[t];
    float s0 = blocksum512(y * cls_w[t * 2 + 0], red, lane, wid);
    float s1 = blocksum512(y * cls_w[t * 2 + 1], red, lane, wid);
    if (t == 0) { out[0] = s0 + cls_b[0]; out[1] = s1 + cls_b[1]; }
}

extern "C" void kernel_launch(void* const* d_in, const int* in_sizes, int n_in,
                              void* d_out, int out_size, void* d_ws, size_t ws_size,
                              hipStream_t stream) {
    (void)in_sizes; (void)n_in; (void)out_size; (void)ws_size;
    const float* feats = (const float*)d_in[0];
    const float* fc1_w = (const float*)d_in[1];
    const float* fc1_b = (const float*)d_in[2];
    const float* wh_w  = (const float*)d_in[3];
    const float* wh_b  = (const float*)d_in[4];
    const float* wt_w  = (const float*)d_in[5];
    const float* wt_b  = (const float*)d_in[6];
    const float* l1_w  = (const float*)d_in[7];
    const float* l1_b  = (const float*)d_in[8];
    const float* l2_w  = (const float*)d_in[9];
    const float* l2_b  = (const float*)d_in[10];
    const float* ln_g  = (const float*)d_in[11];
    const float* ln_b  = (const float*)d_in[12];
    const float* cls_w = (const float*)d_in[13];
    const float* cls_b = (const float*)d_in[14];

    char* ws = (char*)d_ws;
    size_t off = 0;
    auto alloc = [&](size_t bytes) {
        char* p = ws + off;
        off += (bytes + 255) & ~(size_t)255;
        return p;
    };
    unsigned short* fb   = (unsigned short*)alloc(8192ull * 384 * 2);
    unsigned short* xb   = (unsigned short*)alloc(8192ull * 512 * 2);
    unsigned short* ehb  = (unsigned short*)alloc(8192ull * 512 * 2);
    unsigned short* etb  = (unsigned short*)alloc(8192ull * 512 * 2);
    unsigned short* sb   = (unsigned short*)alloc(8192ull * 512 * 2);
    unsigned short* pb   = (unsigned short*)alloc(8192ull * 512 * 2);
    unsigned short* wfc1T = (unsigned short*)alloc(512ull * 384 * 2);
    unsigned short* whT  = (unsigned short*)alloc(512ull * 512 * 2);
    unsigned short* wtT  = (unsigned short*)alloc(512ull * 512 * 2);
    unsigned short* l1T  = (unsigned short*)alloc(512ull * 512 * 2);
    unsigned short* l2T  = (unsigned short*)alloc(512ull * 512 * 2);
    float* colsum     = (float*)alloc(512 * 4);
    float* colsum_emb = (float*)alloc(512 * 4);
    float* cvh = (float*)alloc(512 * 4);
    float* cvt = (float*)alloc(512 * 4);
    unsigned* pk = (unsigned*)alloc(8192ull * 8 * 6 * 4);

    hipMemsetAsync(colsum, 0, 512 * 4, stream);
    hipMemsetAsync(colsum_emb, 0, 512 * 4, stream);

    // fused conv + 5 LDS-tiled weight transposes (wh/wt scaled 0.5)
    k_prep<<<dim3(256, 1, 6), 256, 0, stream>>>(
        feats, fc1_w, wh_w, wt_w, l1_w, l2_w, fb, wfc1T, whT, wtT, l1T, l2T);

    // x0 = lrelu(feats@fc1 + b), colsum(x0)  [xb holds x0; mean folded into bias below]
    k_gemm<1, 1><<<dim3(64, 4, 1), 256, 0, stream>>>(
        fb, fb, wfc1T, wfc1T, fc1_b, fc1_b, xb, xb, colsum, 8192, 512, 384);
    // rank-1 fold: cv = b + (1/8192)*colsum@(0.5W) via L2-hot bf16 whT/wtT
    k_rank1<<<dim3(64, 2), 512, 0, stream>>>(colsum, whT, wtT, wh_b, wt_b, cvh, cvt);
    // e_h and e_t in one dual launch: e = x0 @ (0.5W) + cv
    k_gemm<0, 0><<<dim3(64, 4, 2), 256, 0, stream>>>(
        xb, xb, whT, wtT, cvh, cvt, ehb, etb, nullptr, 8192, 512, 512);
    // attn logits + fused in-register top-6 (128x128 tiles, 8 col-splits)
    k_attn_topk<<<dim3(64, 8), 256, 0, stream>>>(ehb, etb, pk);
    // neighbor aggregation (fused 48-key merge) -> s = e_h + e_Nh, p = e_h * e_Nh (bf16)
    k_agg<<<2048, 256, 0, stream>>>(ehb, etb, pk, sb, pb);
    // emb colsums in one dual launch (never materialize emb)
    k_gemm<1, 2><<<dim3(64, 4, 2), 256, 0, stream>>>(
        sb, pb, l1T, l2T, l1_b, l2_b, nullptr, nullptr, colsum_emb, 8192, 512, 512);
    // mean -> LN -> classifier
    k_final<<<1, 512, 0, stream>>>(colsum_emb, ln_g, ln_b, cls_w, cls_b, (float*)d_out);
}